// Round 3
// baseline (138.957 us; speedup 1.0000x reference)
//
#include <hip/hip_runtime.h>
#include <hip/hip_bf16.h>

typedef unsigned short u16;
typedef unsigned int u32;

#define THREADS 256
constexpr int CH = 64;        // in/out channels
constexpr int PP = 32;        // neighbors per point
constexpr int TM = 16;        // points per block

// ---- LDS layout (bytes) ----
// W:  [16 m][16 g][32 p] bf16, A-fragment order = 16384
// Mb: [8 pt][1024 k] bf16, XOR-swizzled (byte ^= ((row&7)^(g&7))<<4) = 16384
constexpr int W_OFF  = 0;
constexpr int MB_OFF = 16384;
constexpr int LDS_BYTES = 32768;   // exactly 5 blocks/CU at 160 KiB

typedef __attribute__((ext_vector_type(8))) short short8;
typedef __attribute__((ext_vector_type(4))) float f32x4;

static __device__ __forceinline__ u16 f2bf_rne(float f) {
  __hip_bfloat16 h = __float2bfloat16(f);
  return __builtin_bit_cast(u16, h);
}
static __device__ __forceinline__ u16 rbf(float f) {  // cheap round-half-up (2 VALU)
  u32 u = __builtin_bit_cast(u32, f);
  return (u16)((u + 0x8000u) >> 16);
}

// ---- prep 1: features f32 -> bf16 ----
__global__ void prep_feat(const float* __restrict__ in, u16* __restrict__ outb, int n2) {
  int i = blockIdx.x * blockDim.x + threadIdx.x;
  if (i < n2) {
    float2 v = ((const float2*)in)[i];
    u32 u = (u32)f2bf_rne(v.x) | ((u32)f2bf_rne(v.y) << 16);
    ((u32*)outb)[i] = u;
  }
}

// ---- prep 2: kernel f32 [g][i][o] -> bf16 in B-fragment order ----
__global__ void prep_k2f(const float* __restrict__ kern, u16* __restrict__ k2f) {
  int d = blockIdx.x * blockDim.x + threadIdx.x;   // 65536 total
  int e = d & 7, l = (d >> 3) & 63, ot = (d >> 9) & 3, ks = d >> 11;
  int k = ks * 32 + (l >> 4) * 8 + e;
  int o = ot * 16 + (l & 15);
  k2f[d] = f2bf_rne(kern[k * 64 + o]);
}

// ---- main fused kernel: 16 points per block, 4 waves, 5 blocks/CU ----
__global__ __launch_bounds__(THREADS, 5) void cconv_main(
    const int* __restrict__ recv, const float* __restrict__ relpos,
    const float* __restrict__ wsup, const int* __restrict__ aptr,
    const u16* __restrict__ fbf, const u16* __restrict__ k2f,
    const float* __restrict__ bias, float* __restrict__ out) {
  __shared__ __align__(16) char smem[LDS_BYTES];
  const int tid = threadIdx.x;
  const int n0 = blockIdx.x * TM;
  const int wid = tid >> 6, lane = tid & 63;
  const int l15 = lane & 15, l4 = lane >> 4;

  // ---- prefetch receivers for h=0 (hide latency under P0) ----
  const int* rbase = recv + n0 * PP + l4 * 8;
  const int4 a00 = *(const int4*)(rbase + (wid * 2 + 0) * PP);
  const int4 b00 = *(const int4*)(rbase + (wid * 2 + 0) * PP + 4);
  const int4 a01 = *(const int4*)(rbase + (wid * 2 + 1) * PP);
  const int4 b01 = *(const int4*)(rbase + (wid * 2 + 1) * PP + 4);

  // ---- P0: full W matrix -> LDS in A-fragment order [m][g][p] bf16 ----
  {
    const float invws = 1.0f / wsup[0];
    int a = aptr[0];
    if (a < 0 || a > 64) a = (int)(*(const float*)aptr);  // dtype fallback
    const int m0 = tid >> 4, p2 = (tid & 15) * 2;         // 2 edges per thread
    const float4 rp4 = *(const float4*)(relpos + ((n0 + m0) * PP + p2) * 2);
    float wy[2][4], wx[2][4];
    #pragma unroll
    for (int s = 0; s < 2; ++s) {
      const float rx = (s ? rp4.z : rp4.x) * invws;
      const float ry = (s ? rp4.w : rp4.y) * invws;
      const float d2 = rx * rx + ry * ry;
      const float w1 = fmaxf(1.0f - d2, 0.0f);
      float win = 1.0f;
      for (int q = 0; q < a; ++q) win *= w1;
      float gy = fminf(fmaxf((rx + 1.0f) * 1.5f, 0.0f), 3.0f);
      float gx = fminf(fmaxf((ry + 1.0f) * 1.5f, 0.0f), 3.0f);
      int y0 = (int)gy; y0 = y0 > 2 ? 2 : y0;
      int x0 = (int)gx; x0 = x0 > 2 ? 2 : x0;
      const float fy = gy - (float)y0, fx = gx - (float)x0;
      #pragma unroll
      for (int y = 0; y < 4; ++y)
        wy[s][y] = win * ((y == y0) ? (1.0f - fy) : (y == y0 + 1) ? fy : 0.0f);
      #pragma unroll
      for (int x = 0; x < 4; ++x)
        wx[s][x] = (x == x0) ? (1.0f - fx) : (x == x0 + 1) ? fx : 0.0f;
    }
    u32* wrow = (u32*)(smem + W_OFF) + m0 * 256 + (p2 >> 1);
    #pragma unroll
    for (int g = 0; g < 16; ++g) {
      const int y = g >> 2, x = g & 3;
      wrow[g * 16] = (u32)rbf(wy[0][y] * wx[0][x]) | ((u32)rbf(wy[1][y] * wx[1][x]) << 16);
    }
  }
  __syncthreads();

  // build one point's M and stage into Mb (XOR-swizzled)
  auto build = [&](const int m, const int mloc, const int4 A4, const int4 B4) {
    const short8 af = *(const short8*)(smem + W_OFF + m * 1024 + l15 * 64 + l4 * 16);
    const int rv[8] = {A4.x, A4.y, A4.z, A4.w, B4.x, B4.y, B4.z, B4.w};
    u32 vo[8];
    #pragma unroll
    for (int e = 0; e < 8; ++e) vo[e] = (u32)rv[e] * 64u + (u32)l15;
    f32x4 accm[4];
    #pragma unroll
    for (int ib = 0; ib < 4; ++ib) {
      u32 q[8];
      #pragma unroll
      for (int e = 0; e < 8; ++e) q[e] = (u32)fbf[vo[e] + ib * 16];
      union { u32 u[4]; short8 s; } bb;
      #pragma unroll
      for (int j = 0; j < 4; ++j) bb.u[j] = q[2 * j] | (q[2 * j + 1] << 16);
      const f32x4 cz = {0.f, 0.f, 0.f, 0.f};
      accm[ib] = __builtin_amdgcn_mfma_f32_16x16x32_bf16(af, bb.s, cz, 0, 0, 0);
    }
    #pragma unroll
    for (int ib = 0; ib < 4; ++ib)
      #pragma unroll
      for (int r = 0; r < 4; ++r) {
        const int g = l4 * 4 + r;
        const u32 k = (u32)(g * 64 + ib * 16 + l15);
        u32 byt = (u32)mloc * 2048u + k * 2u;
        byt ^= ((u32)((mloc & 7) ^ (g & 7)) << 4);
        *(u16*)(smem + MB_OFF + byt) = rbf(accm[ib][r]);
      }
  };

  // half GEMM: acc[16n x 16o] += Mb[16(dup8) x 1024k] @ K2[1024k x 64o], unmasked
  auto gemm = [&](f32x4& acc) {
    const u32 rowb = (u32)(l15 & 7) * 2048u;
    const u32 swl = (u32)(l15 & 7) << 4;
    #pragma unroll
    for (int ks = 0; ks < 32; ++ks) {
      const u32 kc = (u32)ks * 32u + (u32)l4 * 8u;
      const u32 g7 = (((kc >> 6) & 7u) << 4);
      const u32 byt = (rowb + kc * 2u) ^ swl ^ g7;
      const short8 a2 = *(const short8*)(smem + MB_OFF + byt);
      const short8 b2 = *(const short8*)(k2f + ((u32)(ks * 4 + wid) * 64u + (u32)lane) * 8u);
      acc = __builtin_amdgcn_mfma_f32_16x16x32_bf16(a2, b2, acc, 0, 0, 0);
    }
  };

  f32x4 accA = {0.f, 0.f, 0.f, 0.f}, accB = {0.f, 0.f, 0.f, 0.f};

  // h = 0
  build(wid * 2 + 0, wid * 2 + 0, a00, b00);
  build(wid * 2 + 1, wid * 2 + 1, a01, b01);
  // prefetch h=1 receivers; latency hides under GEMM h0
  const int4 a10 = *(const int4*)(rbase + (8 + wid * 2 + 0) * PP);
  const int4 b10 = *(const int4*)(rbase + (8 + wid * 2 + 0) * PP + 4);
  const int4 a11 = *(const int4*)(rbase + (8 + wid * 2 + 1) * PP);
  const int4 b11 = *(const int4*)(rbase + (8 + wid * 2 + 1) * PP + 4);
  __syncthreads();
  gemm(accA);
  __syncthreads();
  // h = 1
  build(8 + wid * 2 + 0, wid * 2 + 0, a10, b10);
  build(8 + wid * 2 + 1, wid * 2 + 1, a11, b11);
  __syncthreads();
  gemm(accB);

  // ---- epilogue: rows n = l4*4 + r; lanes l4<2 own points 0-7 (accA), l4>=2 points 8-15 (accB)
  const int o = wid * 16 + l15;
  const float bv = bias[o];
  const f32x4 accw = (l4 < 2) ? accA : accB;
  #pragma unroll
  for (int r = 0; r < 4; ++r)
    out[(n0 + l4 * 4 + r) * CH + o] = accw[r] * (1.0f / 32.0f) + bv;
}

extern "C" void kernel_launch(void* const* d_in, const int* in_sizes, int n_in,
                              void* d_out, int out_size, void* d_ws, size_t ws_size,
                              hipStream_t stream) {
  const float* features = (const float*)d_in[0];
  const int* receivers  = (const int*)d_in[1];
  const float* relpos   = (const float*)d_in[2];
  const float* wsup     = (const float*)d_in[3];
  const int* aptr       = (const int*)d_in[4];
  const float* kern     = (const float*)d_in[5];
  const float* bias     = (const float*)d_in[6];
  float* out = (float*)d_out;

  const int N = in_sizes[0] / CH;   // 50000
  u16* fbf = (u16*)d_ws;                                    // N*64 bf16 = 6.4 MB
  u16* k2f = (u16*)((char*)d_ws + (size_t)N * CH * 2);      // 128 KB, frag-ordered

  const int nfeat2 = in_sizes[0] / 2;
  prep_feat<<<dim3((nfeat2 + 255) / 256), dim3(256), 0, stream>>>(features, fbf, nfeat2);
  prep_k2f<<<dim3(65536 / 256), dim3(256), 0, stream>>>(kern, k2f);

  cconv_main<<<dim3(N / TM), dim3(THREADS), 0, stream>>>(
      receivers, relpos, wsup, aptr, fbf, k2f, bias, out);
}